// Round 1
// baseline (1249.002 us; speedup 1.0000x reference)
//
#include <hip/hip_runtime.h>
#include <hip/hip_bf16.h>

#define BATCH 256
#define TLEN  512
#define DIN   64
#define HID   128
#define GATES 512   // 4*HID
#define NOUT  40

typedef _Float16 h2_t __attribute__((ext_vector_type(2)));

__device__ __forceinline__ unsigned pack_h2(float a, float b) {
    h2_t v; v[0] = (_Float16)a; v[1] = (_Float16)b;
    return __builtin_bit_cast(unsigned, v);
}

__device__ __forceinline__ float fdot2(unsigned a, unsigned b, float c) {
#if __has_builtin(__builtin_amdgcn_fdot2)
    return __builtin_amdgcn_fdot2(__builtin_bit_cast(h2_t, a),
                                  __builtin_bit_cast(h2_t, b), c, false);
#else
    h2_t x = __builtin_bit_cast(h2_t, a), y = __builtin_bit_cast(h2_t, b);
    return fmaf((float)x[1], (float)y[1], fmaf((float)x[0], (float)y[0], c));
#endif
}

__device__ __forceinline__ float sigmoidf_(float x) {
    return 1.0f / (1.0f + __expf(-x));
}
__device__ __forceinline__ float tanhf_(float x) {
    float ax = fabsf(x);
    float e  = __expf(-2.0f * ax);      // in (0,1], never overflows
    float t  = (1.0f - e) / (1.0f + e);
    return copysignf(t, x);
}

// ---------------- Layer 0: x[B,T,64] -> y0 chunk [Tc,B,128] (f16) ----------------
// One block per batch element. Thread j owns gate row j (weights in VGPRs).
__global__ __launch_bounds__(512, 2) void lstm_l0(
    const float* __restrict__ x,
    const float* __restrict__ Wih, const float* __restrict__ Whh,
    const float* __restrict__ bih, const float* __restrict__ bhh,
    float* __restrict__ hstate, float* __restrict__ cstate,
    _Float16* __restrict__ y0, int t0, int t1)
{
    const int b = blockIdx.x;
    const int j = threadIdx.x;

    __shared__ __align__(16) unsigned xs2[DIN / 2];   // x_t packed f16 pairs
    __shared__ __align__(16) float    hlds[HID];      // h (f32, recurrent path)
    __shared__ __align__(16) float    gates[GATES];

    // Persistent weights: Wih row packed f16 (feed-forward), Whh row f32 (recurrent)
    unsigned wx[DIN / 2];
    float    wh[HID];
    {
        const float4* wr = reinterpret_cast<const float4*>(Wih + (size_t)j * DIN);
        #pragma unroll
        for (int q = 0; q < DIN / 4; ++q) {
            float4 v = wr[q];
            wx[2 * q]     = pack_h2(v.x, v.y);
            wx[2 * q + 1] = pack_h2(v.z, v.w);
        }
        const float4* wr2 = reinterpret_cast<const float4*>(Whh + (size_t)j * HID);
        #pragma unroll
        for (int q = 0; q < HID / 4; ++q) {
            float4 v = wr2[q];
            wh[4 * q] = v.x; wh[4 * q + 1] = v.y; wh[4 * q + 2] = v.z; wh[4 * q + 3] = v.w;
        }
    }
    const float bias = bih[j] + bhh[j];

    float c = 0.f, hreg = 0.f;
    if (j < HID) {
        c    = cstate[b * HID + j];
        hreg = hstate[b * HID + j];
        hlds[j] = hreg;
    }
    if (j >= 256 && j < 256 + DIN / 2) {
        int k = j - 256;
        float2 v = reinterpret_cast<const float2*>(x + ((size_t)b * TLEN + t0) * DIN)[k];
        xs2[k] = pack_h2(v.x, v.y);
    }
    __syncthreads();

    for (int t = t0; t < t1; ++t) {
        float acc = bias;
        // x-projection: packed f16 dot2 (feed-forward only)
        const uint4* xv = reinterpret_cast<const uint4*>(xs2);
        #pragma unroll
        for (int q = 0; q < DIN / 8; ++q) {
            uint4 v = xv[q];
            acc = fdot2(wx[4 * q + 0], v.x, acc);
            acc = fdot2(wx[4 * q + 1], v.y, acc);
            acc = fdot2(wx[4 * q + 2], v.z, acc);
            acc = fdot2(wx[4 * q + 3], v.w, acc);
        }
        // h-projection: f32 FMA (recurrent path stays full precision)
        const float4* hv = reinterpret_cast<const float4*>(hlds);
        #pragma unroll
        for (int q = 0; q < HID / 4; ++q) {
            float4 v = hv[q];
            acc = fmaf(wh[4 * q + 0], v.x, acc);
            acc = fmaf(wh[4 * q + 1], v.y, acc);
            acc = fmaf(wh[4 * q + 2], v.z, acc);
            acc = fmaf(wh[4 * q + 3], v.w, acc);
        }
        gates[j] = acc;
        __syncthreads();

        if (j < HID) {
            float gi = gates[j], gf = gates[j + HID], gg = gates[j + 2 * HID], go = gates[j + 3 * HID];
            float iv = sigmoidf_(gi), fv = sigmoidf_(gf), gv = tanhf_(gg), ov = sigmoidf_(go);
            c = fmaf(fv, c, iv * gv);
            float h = ov * tanhf_(c);
            hreg = h;
            hlds[j] = h;
            y0[((size_t)(t - t0) * BATCH + b) * HID + j] = (_Float16)h;
        }
        if (j >= 256 && j < 256 + DIN / 2 && t + 1 < t1) {
            int k = j - 256;
            float2 v = reinterpret_cast<const float2*>(x + ((size_t)b * TLEN + (t + 1)) * DIN)[k];
            xs2[k] = pack_h2(v.x, v.y);
        }
        __syncthreads();
    }
    if (j < HID) {
        cstate[b * HID + j] = c;
        hstate[b * HID + j] = hreg;
    }
}

// ---------------- Layer 1: y0 chunk (f16) -> h1/c1 state ----------------
__global__ __launch_bounds__(512, 2) void lstm_l1(
    const _Float16* __restrict__ y0,
    const float* __restrict__ Wih, const float* __restrict__ Whh,
    const float* __restrict__ bih, const float* __restrict__ bhh,
    float* __restrict__ hstate, float* __restrict__ cstate,
    int t0, int t1)
{
    const int b = blockIdx.x;
    const int j = threadIdx.x;

    __shared__ __align__(16) unsigned xs2[HID / 2];
    __shared__ __align__(16) float    hlds[HID];
    __shared__ __align__(16) float    gates[GATES];

    unsigned wx[HID / 2];
    float    wh[HID];
    {
        const float4* wr = reinterpret_cast<const float4*>(Wih + (size_t)j * HID);
        #pragma unroll
        for (int q = 0; q < HID / 4; ++q) {
            float4 v = wr[q];
            wx[2 * q]     = pack_h2(v.x, v.y);
            wx[2 * q + 1] = pack_h2(v.z, v.w);
        }
        const float4* wr2 = reinterpret_cast<const float4*>(Whh + (size_t)j * HID);
        #pragma unroll
        for (int q = 0; q < HID / 4; ++q) {
            float4 v = wr2[q];
            wh[4 * q] = v.x; wh[4 * q + 1] = v.y; wh[4 * q + 2] = v.z; wh[4 * q + 3] = v.w;
        }
    }
    const float bias = bih[j] + bhh[j];

    float c = 0.f, hreg = 0.f;
    if (j < HID) {
        c    = cstate[b * HID + j];
        hreg = hstate[b * HID + j];
        hlds[j] = hreg;
    }
    const unsigned* y0u = reinterpret_cast<const unsigned*>(y0);
    if (j >= 256 && j < 256 + HID / 2) {
        int k = j - 256;
        xs2[k] = y0u[((size_t)0 * BATCH + b) * (HID / 2) + k];
    }
    __syncthreads();

    for (int t = t0; t < t1; ++t) {
        const int rel = t - t0;
        float acc = bias;
        const uint4* xv = reinterpret_cast<const uint4*>(xs2);
        #pragma unroll
        for (int q = 0; q < HID / 8; ++q) {
            uint4 v = xv[q];
            acc = fdot2(wx[4 * q + 0], v.x, acc);
            acc = fdot2(wx[4 * q + 1], v.y, acc);
            acc = fdot2(wx[4 * q + 2], v.z, acc);
            acc = fdot2(wx[4 * q + 3], v.w, acc);
        }
        const float4* hv = reinterpret_cast<const float4*>(hlds);
        #pragma unroll
        for (int q = 0; q < HID / 4; ++q) {
            float4 v = hv[q];
            acc = fmaf(wh[4 * q + 0], v.x, acc);
            acc = fmaf(wh[4 * q + 1], v.y, acc);
            acc = fmaf(wh[4 * q + 2], v.z, acc);
            acc = fmaf(wh[4 * q + 3], v.w, acc);
        }
        gates[j] = acc;
        __syncthreads();

        if (j < HID) {
            float gi = gates[j], gf = gates[j + HID], gg = gates[j + 2 * HID], go = gates[j + 3 * HID];
            float iv = sigmoidf_(gi), fv = sigmoidf_(gf), gv = tanhf_(gg), ov = sigmoidf_(go);
            c = fmaf(fv, c, iv * gv);
            float h = ov * tanhf_(c);
            hreg = h;
            hlds[j] = h;
        }
        if (j >= 256 && j < 256 + HID / 2 && t + 1 < t1) {
            int k = j - 256;
            xs2[k] = y0u[((size_t)(rel + 1) * BATCH + b) * (HID / 2) + k];
        }
        __syncthreads();
    }
    if (j < HID) {
        cstate[b * HID + j] = c;
        hstate[b * HID + j] = hreg;
    }
}

// ---------------- Final FC: out[b,o] = h1[b,:] @ Wfc[o,:] + bfc[o] ----------------
__global__ __launch_bounds__(128) void fc_kernel(
    const float* __restrict__ h1, const float* __restrict__ Wfc,
    const float* __restrict__ bfc, float* __restrict__ out)
{
    const int b = blockIdx.x;
    const int o = threadIdx.x;
    __shared__ float hs[HID];
    hs[o] = h1[b * HID + o];
    __syncthreads();
    if (o < NOUT) {
        const float* w = Wfc + o * HID;
        float acc = bfc[o];
        #pragma unroll
        for (int k = 0; k < HID; ++k) acc = fmaf(w[k], hs[k], acc);
        out[b * NOUT + o] = acc;
    }
}

extern "C" void kernel_launch(void* const* d_in, const int* in_sizes, int n_in,
                              void* d_out, int out_size, void* d_ws, size_t ws_size,
                              hipStream_t stream) {
    const float* x    = (const float*)d_in[0];
    const float* Wih0 = (const float*)d_in[1];
    const float* Whh0 = (const float*)d_in[2];
    const float* bih0 = (const float*)d_in[3];
    const float* bhh0 = (const float*)d_in[4];
    const float* Wih1 = (const float*)d_in[5];
    const float* Whh1 = (const float*)d_in[6];
    const float* bih1 = (const float*)d_in[7];
    const float* bhh1 = (const float*)d_in[8];
    const float* Wfc  = (const float*)d_in[9];
    const float* bfc  = (const float*)d_in[10];
    float* out = (float*)d_out;

    // Workspace layout: h0, c0, h1, c1 states (f32) then y0 chunk (f16)
    float* h0 = (float*)d_ws;
    float* c0 = h0 + BATCH * HID;
    float* h1 = c0 + BATCH * HID;
    float* c1 = h1 + BATCH * HID;
    _Float16* y0 = (_Float16*)(c1 + BATCH * HID);

    const size_t stateBytes = (size_t)4 * BATCH * HID * sizeof(float);   // 512 KB
    size_t avail = ws_size > stateBytes ? ws_size - stateBytes : 0;
    int Tc = (int)(avail / ((size_t)BATCH * HID * sizeof(_Float16)));
    if (Tc > TLEN) Tc = TLEN;
    if (Tc < 1) Tc = 1;

    hipMemsetAsync(d_ws, 0, stateBytes, stream);

    for (int t0 = 0; t0 < TLEN; t0 += Tc) {
        int t1 = t0 + Tc; if (t1 > TLEN) t1 = TLEN;
        lstm_l0<<<BATCH, 512, 0, stream>>>(x, Wih0, Whh0, bih0, bhh0, h0, c0, y0, t0, t1);
        lstm_l1<<<BATCH, 512, 0, stream>>>(y0, Wih1, Whh1, bih1, bhh1, h1, c1, t0, t1);
    }
    fc_kernel<<<BATCH, 128, 0, stream>>>(h1, Wfc, bfc, out);
}